// Round 3
// baseline (776.564 us; speedup 1.0000x reference)
//
#include <hip/hip_runtime.h>

#define K_CODES 4096
#define DIM 256
#define SEQ 2048
#define NTOK 65536

typedef __bf16 bf16x8 __attribute__((ext_vector_type(8)));
typedef float floatx4 __attribute__((ext_vector_type(4)));
typedef unsigned short u16x8 __attribute__((ext_vector_type(8)));

__device__ __forceinline__ unsigned short f2bf(float f) {
    union { float f; unsigned int u; } v; v.f = f;
    unsigned int u = v.u;
    unsigned int r = u + 0x7fffu + ((u >> 16) & 1u);   // RNE
    return (unsigned short)(r >> 16);
}

// async global->LDS, 16B per lane. LDS dest = wave-uniform base + lane*16.
__device__ __forceinline__ void async_cp16(const void* g, const void* lds_base) {
    typedef __attribute__((address_space(1))) const unsigned int guint;
    typedef __attribute__((address_space(3))) unsigned int luint;
    __builtin_amdgcn_global_load_lds(
        (guint*)(unsigned long long)g,
        (luint*)(unsigned int)(unsigned long long)lds_base,
        16, 0, 0);
}

// ---------------- kernel 1: swizzled bf16 codebook + norms + ws init --------
// cb_swz[((gc*16 + ns*8 + ks)*64 + quad*16 + col)*8 + j]
//   = bf16(codebook[gc*32 + ns*16 + col][quad*8 + ks*32 + j])      (16x16x32 B-frag)
// norms[row] = ||e||^2 + 0.25. Also inits merged[] = 0xFFFFFFFF, counters = 0,
// loss_slot = 0 (re-initialized every graph replay).
__global__ __launch_bounds__(256) void k_prep(const float* __restrict__ cb,
        unsigned short* __restrict__ cb_swz, float* __restrict__ norms,
        unsigned int* __restrict__ merged, unsigned int* __restrict__ counters,
        float* __restrict__ loss_slot) {
    const int c = blockIdx.x;
    const int t = threadIdx.x;
    const int row_loc = t >> 3;       // 0..31 code within chunk
    const int ks = t & 7;             // k-slice
    const int row = c * 32 + row_loc;
    const float* src = cb + (size_t)row * DIM + ks * 32;
    float vals[32];
    float s = 0.0f;
    #pragma unroll
    for (int i = 0; i < 8; ++i) {
        floatx4 v = *(const floatx4*)(src + i * 4);
        #pragma unroll
        for (int j = 0; j < 4; ++j) { vals[i * 4 + j] = v[j]; s += v[j] * v[j]; }
    }
    const int ns = row_loc >> 4, col = row_loc & 15;
    #pragma unroll
    for (int quad = 0; quad < 4; ++quad) {
        u16x8 p;
        #pragma unroll
        for (int j = 0; j < 8; ++j) p[j] = f2bf(vals[quad * 8 + j]);
        *(u16x8*)(cb_swz + ((size_t)((c * 16 + ns * 8 + ks) * 64 + quad * 16 + col)) * 8) = p;
    }
    s += __shfl_xor(s, 1); s += __shfl_xor(s, 2); s += __shfl_xor(s, 4);
    if (ks == 0) norms[row] = s + 0.25f;
    // workspace init: 32768 threads cover 65536 uints as 8B stores
    const int g = c * 256 + t;
    *(unsigned long long*)(merged + 2 * g) = 0xFFFFFFFFFFFFFFFFull;
    if (g < 256) counters[g] = 0u;
    if (g == 0) *loss_slot = 0.0f;
}

// ---------------- kernel 2: MFMA argmin + atomic merge + inline gather ------
// 256 thr = 4 waves, 256 tokens/block (64/wave, m=4), codes split in halves:
// grid 512 = 2 blocks/CU. Twin blocks (same tokens, h=0/1) are XCD-paired by
// the blockIdx remap (8 apart -> same XCD L2 for X reads + merge atomics).
// Round-0 loop schedule (single __syncthreads/chunk = minimal wait: only the
// 4 prior global_load_lds outstanding), 2-deep ring, prefetch depth 1,
// 16x16x32 MFMA (spill-free, 104 VGPR). Round-1 staging swizzle kept
// (bank conflicts 7.6M -> 295K). NEW: packed keys atomicMin'd into merged[];
// the twin finishing SECOND (per-token-block atomic counter) owns the final
// argmin and does gather + output write + distance loss inline, overlapped
// with other blocks' MFMA loops. k_gather dispatch eliminated.
__global__ __launch_bounds__(256, 2) void k_argmin(const float* __restrict__ x,
        const unsigned short* __restrict__ cb_swz, const float* __restrict__ cb,
        const float* __restrict__ norms, unsigned int* __restrict__ merged,
        unsigned int* __restrict__ counters, float* __restrict__ out,
        float* __restrict__ loss_slot) {
    __shared__ __align__(16) char smem[57880];
    unsigned short* xs = (unsigned short*)smem;                 // 16896 B
    unsigned short* ring0 = (unsigned short*)(smem + 16896);    // 16384 B
    unsigned short* ring1 = (unsigned short*)(smem + 33280);    // 16384 B
    float* norms_s = (float*)(smem + 49664);                    //  8192 B
    float* wpart = (float*)(smem + 57856);                      //    16 B
    int* flag_s = (int*)(smem + 57872);                         //     4 B
    // gather-phase overlay (loop data dead by then):
    float* rows_s = (float*)smem;                               // 33024 B
    int* sidx_s = (int*)(smem + 33024);                         //  1024 B

    const int t = threadIdx.x;
    const int lane = t & 63, w = t >> 6;
    const int col = lane & 15, quad = lane >> 4;
    // XCD pairing: twins (same tbid, h=0/1) are 8 apart in blockIdx -> same
    // XCD under round-robin dispatch. Bijection for grid 512.
    const int bid = blockIdx.x;
    const int tbid = (bid & 7) * 32 + (bid >> 4);
    const int h = (bid >> 3) & 1;
    const int tb = tbid * 256;
    const int b = tb >> 11, s0 = tb & 2047;
    const float* xin = x + (size_t)b * DIM * SEQ;

    // prefetch B chunk 0 of this half into ring0
    {
        const char* src = (const char*)cb_swz + (size_t)h * 64 * 16384;
        #pragma unroll
        for (int i = 0; i < 4; ++i)
            async_cp16(src + i * 4096 + w * 1024 + lane * 16,
                       (char*)ring0 + i * 4096 + w * 1024);
    }
    // norms -> LDS once
    {
        const float* ng = norms + h * 2048;
        *(floatx4*)&norms_s[t * 8]     = *(const floatx4*)(ng + t * 8);
        *(floatx4*)&norms_s[t * 8 + 4] = *(const floatx4*)(ng + t * 8 + 4);
    }

    // ---- X staging: 8 phases x 32 tokens; wave p>>1 grabs M-tiles (p&1)*2..+1.
    // Element (tok,d) at xs[tok*264 + ((d>>3)^(tok>>2 &7))*8 + (d&7)]  (swizzled).
    bf16x8 af[4][8];
    float a2 = 0.0f;
    const int q = t & 7, dgp = t >> 3, sq = q * 4;
    for (int p = 0; p < 8; ++p) {
        const int sbase = s0 + p * 32 + sq;
        #pragma unroll
        for (int i = 0; i < 8; ++i) {
            const int d = i * 32 + dgp;
            floatx4 v = *(const floatx4*)(xin + (size_t)d * SEQ + sbase);
            a2 += v[0]*v[0] + v[1]*v[1] + v[2]*v[2] + v[3]*v[3];
            const int chs = (d >> 3) ^ q;            // swizzled 16B chunk
            #pragma unroll
            for (int j = 0; j < 4; ++j)
                xs[(sq + j) * 264 + chs * 8 + (d & 7)] = f2bf(-2.0f * v[j]);
        }
        __syncthreads();
        if ((p >> 1) == w) {
            const int mm = (p & 1) * 2;
            #pragma unroll
            for (int m2 = 0; m2 < 2; ++m2) {
                const int row = m2 * 16 + col;       // token within 32-slab
                const int swz = (row >> 2) & 7;
                #pragma unroll
                for (int ks = 0; ks < 8; ++ks)
                    af[mm + m2][ks] = *(const bf16x8*)
                        &xs[row * 264 + ((quad + ks * 4) ^ swz) * 8];
            }
        }
        __syncthreads();
    }
    // block-reduce a2; h==0 blocks contribute ||x||^2 part of the loss
    #pragma unroll
    for (int off = 1; off < 64; off <<= 1) a2 += __shfl_xor(a2, off);
    if (lane == 0) wpart[w] = a2;
    __syncthreads();   // also drains ring0 prefetch on every wave
    if (t == 0 && h == 0)
        atomicAdd(loss_slot,
                  (wpart[0] + wpart[1] + wpart[2] + wpart[3]) * (1.25f / 16777216.0f));

    unsigned int minkey[4][4];
    #pragma unroll
    for (int m = 0; m < 4; ++m)
        #pragma unroll
        for (int r = 0; r < 4; ++r) minkey[m][r] = 0xFFFFFFFFu;

    #pragma unroll 1
    for (int c = 0; c < 64; ++c) {
        __syncthreads();       // ring[c&1] ready; readers of c-1 done (minimal wait)
        if (c < 63) {
            const char* srcp = (const char*)cb_swz + ((size_t)(h * 64) + c + 1) * 16384;
            char* dst = (char*)(((c + 1) & 1) ? ring1 : ring0);
            #pragma unroll
            for (int i = 0; i < 4; ++i)
                async_cp16(srcp + i * 4096 + w * 1024 + lane * 16,
                           dst + i * 4096 + w * 1024);
        }
        const unsigned short* buf = (c & 1) ? ring1 : ring0;
        #pragma unroll
        for (int ns = 0; ns < 2; ++ns) {
            const float nv = norms_s[c * 32 + ns * 16 + col];
            bf16x8 bfrag[8];
            #pragma unroll
            for (int ks = 0; ks < 8; ++ks)     // lane-contiguous 1KB: conflict-free
                bfrag[ks] = *(const bf16x8*)&buf[((ns * 8 + ks) * 64 + lane) * 8];
            floatx4 acc[4];
            #pragma unroll
            for (int m = 0; m < 4; ++m) acc[m] = (floatx4){nv, nv, nv, nv};
            #pragma unroll
            for (int ks = 0; ks < 8; ++ks)
                #pragma unroll
                for (int m = 0; m < 4; ++m)
                    acc[m] = __builtin_amdgcn_mfma_f32_16x16x32_bf16(
                                 af[m][ks], bfrag[ks], acc[m], 0, 0, 0);
            const unsigned int code = (unsigned int)((h * 64 + c) * 32 + ns * 16 + col);
            #pragma unroll
            for (int m = 0; m < 4; ++m)
                #pragma unroll
                for (int r = 0; r < 4; ++r) {
                    unsigned int key = (__float_as_uint(acc[m][r]) & 0xFFFFF000u) | code;
                    minkey[m][r] = key < minkey[m][r] ? key : minkey[m][r];
                }
        }
    }

    // ---- min over 16 column-lanes, atomic-merge packed (dist|code) per token
    #pragma unroll
    for (int m = 0; m < 4; ++m)
        #pragma unroll
        for (int r = 0; r < 4; ++r) {
            unsigned int k = minkey[m][r];
            #pragma unroll
            for (int off = 8; off >= 1; off >>= 1) {
                unsigned int o = __shfl_xor(k, off);
                k = o < k ? o : k;
            }
            if (col == 0)
                atomicMin(&merged[tb + w * 64 + m * 16 + quad * 4 + r], k);
        }

    // ---- twin handshake: second finisher owns the final argmin
    __threadfence();
    if (t == 0) flag_s[0] = (atomicAdd(&counters[tbid], 1u) == 1u) ? 1 : 0;
    __syncthreads();
    if (!flag_s[0]) return;

    // winner: final keys via atomic RMW read (cross-XCD coherent), loss, gather
    unsigned int kk = atomicMin(&merged[tb + t], 0xFFFFFFFFu);
    float dv = __uint_as_float(kk & 0xFFFFF000u) - 0.25f;
    #pragma unroll
    for (int off = 1; off < 64; off <<= 1) dv += __shfl_xor(dv, off);
    __syncthreads();                     // loop LDS dead -> overlay is safe
    sidx_s[t] = (int)(kk & 0xFFFu);
    if (lane == 0) wpart[w] = dv;
    __syncthreads();
    if (t == 0)
        atomicAdd(loss_slot,
                  (wpart[0] + wpart[1] + wpart[2] + wpart[3]) * (1.25f / 16777216.0f));

    // gather: 8 passes x 32 tokens. Stage rows coalesced (floatx4), transpose
    // out of LDS (stride 258: read side 2-way = free; b128 write at LDS floor).
    const int rr = t >> 3, cs8 = (t & 7) * 32;   // stage roles: 8 thr/row
    const int qg = t & 7, dgb = t >> 3;          // write roles
    #pragma unroll 1
    for (int p = 0; p < 8; ++p) {
        if (p) __syncthreads();                  // rows_s WAR between passes
        const float* srcr = cb + (size_t)sidx_s[p * 32 + rr] * DIM + cs8;
        float* dstr = rows_s + rr * 258 + cs8;
        #pragma unroll
        for (int i4 = 0; i4 < 8; ++i4)
            *(floatx4*)(dstr + i4 * 4) = *(const floatx4*)(srcr + i4 * 4);
        __syncthreads();
        #pragma unroll
        for (int i = 0; i < 8; ++i) {
            const int d = i * 32 + dgb;
            floatx4 v;
            #pragma unroll
            for (int k2 = 0; k2 < 4; ++k2) v[k2] = rows_s[(qg * 4 + k2) * 258 + d];
            *(floatx4*)(out + (size_t)b * DIM * SEQ + (size_t)d * SEQ
                        + s0 + p * 32 + qg * 4) = v;
        }
    }
}

extern "C" void kernel_launch(void* const* d_in, const int* in_sizes, int n_in,
                              void* d_out, int out_size, void* d_ws, size_t ws_size,
                              hipStream_t stream) {
    const float* inputs   = (const float*)d_in[0];
    const float* codebook = (const float*)d_in[1];
    float* out = (float*)d_out;
    unsigned short* cb_swz = (unsigned short*)d_ws;                                  // 2 MB
    float* norms = (float*)((char*)d_ws + (size_t)K_CODES * DIM * 2);                // 16 KB
    unsigned int* merged = (unsigned int*)((char*)d_ws + (size_t)K_CODES * DIM * 2
                                           + K_CODES * 4);                           // 256 KB
    unsigned int* counters = merged + NTOK;                                          // 1 KB
    float* loss_slot = out + (out_size - 1);

    hipLaunchKernelGGL(k_prep,   dim3(K_CODES / 32),   dim3(256), 0, stream,
                       codebook, cb_swz, norms, merged, counters, loss_slot);
    hipLaunchKernelGGL(k_argmin, dim3(NTOK / 256 * 2), dim3(256), 0, stream,
                       inputs, cb_swz, codebook, norms, merged, counters, out, loss_slot);
}

// Round 5
// 723.489 us; speedup vs baseline: 1.0734x; 1.0734x over previous
//
#include <hip/hip_runtime.h>

#define K_CODES 4096
#define DIM 256
#define SEQ 2048
#define NTOK 65536

typedef __bf16 bf16x8 __attribute__((ext_vector_type(8)));
typedef float floatx4 __attribute__((ext_vector_type(4)));
typedef unsigned short u16x8 __attribute__((ext_vector_type(8)));

__device__ __forceinline__ unsigned short f2bf(float f) {
    union { float f; unsigned int u; } v; v.f = f;
    unsigned int u = v.u;
    unsigned int r = u + 0x7fffu + ((u >> 16) & 1u);   // RNE
    return (unsigned short)(r >> 16);
}

// async global->LDS, 16B per lane. LDS dest = wave-uniform base + lane*16.
__device__ __forceinline__ void async_cp16(const void* g, const void* lds_base) {
    typedef __attribute__((address_space(1))) const unsigned int guint;
    typedef __attribute__((address_space(3))) unsigned int luint;
    __builtin_amdgcn_global_load_lds(
        (guint*)(unsigned long long)g,
        (luint*)(unsigned int)(unsigned long long)lds_base,
        16, 0, 0);
}

// ---------------- kernel 1: swizzled bf16 codebook + biased norms -----------
// cb_swz[((gc*16 + ns*8 + ks)*64 + quad*16 + col)*8 + j]
//   = bf16(codebook[gc*32 + ns*16 + col][quad*8 + ks*32 + j])
// norms[row] = ||e||^2 + 0.25 (bias keeps dist positive for the packed key).
__global__ __launch_bounds__(256) void k_prep(const float* __restrict__ cb,
        unsigned short* __restrict__ cb_swz, float* __restrict__ norms,
        float* __restrict__ loss_slot) {
    const int c = blockIdx.x;
    const int t = threadIdx.x;
    const int row_loc = t >> 3;       // 0..31 code within chunk
    const int ks = t & 7;             // k-slice
    const int row = c * 32 + row_loc;
    const float* src = cb + (size_t)row * DIM + ks * 32;
    float vals[32];
    float s = 0.0f;
    #pragma unroll
    for (int i = 0; i < 8; ++i) {
        floatx4 v = *(const floatx4*)(src + i * 4);
        #pragma unroll
        for (int j = 0; j < 4; ++j) { vals[i * 4 + j] = v[j]; s += v[j] * v[j]; }
    }
    const int ns = row_loc >> 4, col = row_loc & 15;
    #pragma unroll
    for (int quad = 0; quad < 4; ++quad) {
        u16x8 p;
        #pragma unroll
        for (int j = 0; j < 8; ++j) p[j] = f2bf(vals[quad * 8 + j]);
        *(u16x8*)(cb_swz + ((size_t)((c * 16 + ns * 8 + ks) * 64 + quad * 16 + col)) * 8) = p;
    }
    s += __shfl_xor(s, 1); s += __shfl_xor(s, 2); s += __shfl_xor(s, 4);
    if (ks == 0) norms[row] = s + 0.25f;
    if (c == 0 && t == 0) *loss_slot = 0.0f;
}

// ---------------- kernel 2: MFMA distance GEMM + packed argmin --------------
// Round-0 structure (proven 139us): 256 thr = 4 waves, 256 tokens/block
// (64/wave, m=4), codes split in halves -> grid 512, 2 blocks/CU. Single
// __syncthreads per chunk (minimal wait: only the 4 prior global_load_lds are
// outstanding at the barrier), 2-deep ring, prefetch depth 1, 16x16x32 MFMA
// (spill-free). Round-1 verified add-ons only: XOR-swizzled X staging (bank
// conflicts 7.6M -> 295K) and norms in LDS.
__global__ __launch_bounds__(256, 2) void k_argmin(const float* __restrict__ x,
        const unsigned short* __restrict__ cb_swz, const float* __restrict__ norms,
        unsigned int* __restrict__ halfmin, float* __restrict__ loss_slot) {
    __shared__ __align__(16) unsigned short xs[32 * 264];     // 16896 B
    __shared__ __align__(16) unsigned short ring[2][8192];    // 32768 B
    __shared__ __align__(16) float norms_s[2048];             //  8192 B
    __shared__ float wpart[4];
    const int t = threadIdx.x;
    const int lane = t & 63, w = t >> 6;
    const int col = lane & 15, quad = lane >> 4;
    const int bx = blockIdx.x;
    const int h = bx & 1;                  // code half
    const int tb = (bx >> 1) * 256;        // first token of block
    const int b = tb >> 11, s0 = tb & 2047;
    const float* xin = x + (size_t)b * DIM * SEQ;

    // prefetch B chunk 0 of this half into ring[0] (overlaps X staging)
    {
        const char* src = (const char*)cb_swz + (size_t)h * 64 * 16384;
        #pragma unroll
        for (int i = 0; i < 4; ++i)
            async_cp16(src + i * 4096 + w * 1024 + lane * 16,
                       (char*)ring[0] + i * 4096 + w * 1024);
    }
    // norms -> LDS once
    {
        const float* ng = norms + h * 2048;
        *(floatx4*)&norms_s[t * 8]     = *(const floatx4*)(ng + t * 8);
        *(floatx4*)&norms_s[t * 8 + 4] = *(const floatx4*)(ng + t * 8 + 4);
    }

    // ---- X staging: 8 phases x 32 tokens; wave p>>1 grabs M-tiles (p&1)*2..+1.
    // Element (tok,d) at xs[tok*264 + ((d>>3)^(tok>>2 &7))*8 + (d&7)] (swizzled:
    // 16 writing lanes (token stride 4) spread over all 32 banks -> free).
    bf16x8 af[4][8];
    float a2 = 0.0f;
    const int q = t & 7, dgp = t >> 3, sq = q * 4;
    for (int p = 0; p < 8; ++p) {
        const int sbase = s0 + p * 32 + sq;
        #pragma unroll
        for (int i = 0; i < 8; ++i) {
            const int d = i * 32 + dgp;
            floatx4 v = *(const floatx4*)(xin + (size_t)d * SEQ + sbase);
            a2 += v[0]*v[0] + v[1]*v[1] + v[2]*v[2] + v[3]*v[3];
            const int chs = (d >> 3) ^ q;            // swizzled 16B chunk
            #pragma unroll
            for (int j = 0; j < 4; ++j)
                xs[(sq + j) * 264 + chs * 8 + (d & 7)] = f2bf(-2.0f * v[j]);
        }
        __syncthreads();
        if ((p >> 1) == w) {
            const int mm = (p & 1) * 2;
            #pragma unroll
            for (int m2 = 0; m2 < 2; ++m2) {
                const int row = m2 * 16 + col;       // token within 32-slab
                const int swz = (row >> 2) & 7;
                #pragma unroll
                for (int ks = 0; ks < 8; ++ks)
                    af[mm + m2][ks] = *(const bf16x8*)
                        &xs[row * 264 + ((quad + ks * 4) ^ swz) * 8];
            }
        }
        __syncthreads();
    }
    // block-reduce a2; h==0 blocks contribute ||x||^2 part of the loss
    #pragma unroll
    for (int off = 1; off < 64; off <<= 1) a2 += __shfl_xor(a2, off);
    if (lane == 0) wpart[w] = a2;
    __syncthreads();   // also drains ring[0] prefetch on every wave
    if (t == 0 && h == 0)
        atomicAdd(loss_slot,
                  (wpart[0] + wpart[1] + wpart[2] + wpart[3]) * (1.25f / 16777216.0f));

    unsigned int minkey[4][4];
    #pragma unroll
    for (int m = 0; m < 4; ++m)
        #pragma unroll
        for (int r = 0; r < 4; ++r) minkey[m][r] = 0xFFFFFFFFu;

    #pragma unroll 1
    for (int c = 0; c < 64; ++c) {
        __syncthreads();       // ring[c&1] ready; readers of c-1 done (minimal wait)
        if (c < 63) {
            const char* srcp = (const char*)cb_swz + ((size_t)(h * 64) + c + 1) * 16384;
            char* dst = (char*)ring[(c + 1) & 1];
            #pragma unroll
            for (int i = 0; i < 4; ++i)
                async_cp16(srcp + i * 4096 + w * 1024 + lane * 16,
                           dst + i * 4096 + w * 1024);
        }
        const unsigned short* buf = ring[c & 1];
        #pragma unroll
        for (int ns = 0; ns < 2; ++ns) {
            const float nv = norms_s[c * 32 + ns * 16 + col];
            bf16x8 bfrag[8];
            #pragma unroll
            for (int ks = 0; ks < 8; ++ks)     // lane-contiguous 1KB: conflict-free
                bfrag[ks] = *(const bf16x8*)&buf[((ns * 8 + ks) * 64 + lane) * 8];
            floatx4 acc[4];
            #pragma unroll
            for (int m = 0; m < 4; ++m) acc[m] = (floatx4){nv, nv, nv, nv};
            #pragma unroll
            for (int ks = 0; ks < 8; ++ks)
                #pragma unroll
                for (int m = 0; m < 4; ++m)
                    acc[m] = __builtin_amdgcn_mfma_f32_16x16x32_bf16(
                                 af[m][ks], bfrag[ks], acc[m], 0, 0, 0);
            const unsigned int code = (unsigned int)((h * 64 + c) * 32 + ns * 16 + col);
            #pragma unroll
            for (int m = 0; m < 4; ++m)
                #pragma unroll
                for (int r = 0; r < 4; ++r) {
                    unsigned int key = (__float_as_uint(acc[m][r]) & 0xFFFFF000u) | code;
                    minkey[m][r] = key < minkey[m][r] ? key : minkey[m][r];
                }
        }
    }

    // ---- min over 16 column-lanes, write packed (dist|code) per token
    #pragma unroll
    for (int m = 0; m < 4; ++m)
        #pragma unroll
        for (int r = 0; r < 4; ++r) {
            unsigned int k = minkey[m][r];
            #pragma unroll
            for (int off = 8; off >= 1; off >>= 1) {
                unsigned int o = __shfl_xor(k, off);
                k = o < k ? o : k;
            }
            if (col == 0)
                halfmin[h * NTOK + tb + w * 64 + m * 16 + quad * 4 + r] = k;
        }
}

// ---------------- kernel 3: merge + vectorized gather + loss ----------------
// 256 thr, 128 tokens/block, grid 512. Thread roles: q = t>>3 (token quad:
// tokens q*4..+3), dg = t&7 (d-group). Loads are floatx4 from cb with 128B
// contiguous segments per codebook row (8 dg-lanes x 16B); a 4x4 register
// transpose (static indices) feeds floatx4 stores with 128B contiguous
// segments per output d-row. 4x fewer load instructions than the scalar
// gather; no LDS round-trip.
__global__ __launch_bounds__(256) void k_gather(const float* __restrict__ cb,
        const unsigned int* __restrict__ halfmin, float* __restrict__ out,
        float* __restrict__ loss_slot) {
    __shared__ int sidx[128];
    __shared__ float wp2[2];
    const int t = threadIdx.x;
    const int tb = blockIdx.x * 128;
    const int b = tb >> 11, s0 = tb & 2047;
    if (t < 128) {
        unsigned int k0 = halfmin[tb + t], k1 = halfmin[NTOK + tb + t];
        unsigned int km = k0 < k1 ? k0 : k1;
        sidx[t] = (int)(km & 0xFFFu);
        float dv = __uint_as_float(km & 0xFFFFF000u) - 0.25f;
        #pragma unroll
        for (int off = 1; off < 64; off <<= 1) dv += __shfl_xor(dv, off);
        if ((t & 63) == 0) wp2[t >> 6] = dv;
    }
    __syncthreads();
    if (t == 0) atomicAdd(loss_slot, (wp2[0] + wp2[1]) * (1.25f / 16777216.0f));
    const int q = t >> 3, dg = t & 7;
    int rows[4];
    #pragma unroll
    for (int k = 0; k < 4; ++k) rows[k] = sidx[q * 4 + k];
    float* ob = out + (size_t)b * DIM * SEQ + s0 + q * 4;
    #pragma unroll
    for (int i = 0; i < 8; ++i) {
        const int d0 = i * 32 + dg * 4;
        floatx4 v0 = *(const floatx4*)(cb + (size_t)rows[0] * DIM + d0);
        floatx4 v1 = *(const floatx4*)(cb + (size_t)rows[1] * DIM + d0);
        floatx4 v2 = *(const floatx4*)(cb + (size_t)rows[2] * DIM + d0);
        floatx4 v3 = *(const floatx4*)(cb + (size_t)rows[3] * DIM + d0);
        #pragma unroll
        for (int j = 0; j < 4; ++j) {
            floatx4 o = {v0[j], v1[j], v2[j], v3[j]};
            *(floatx4*)(ob + (size_t)(d0 + j) * SEQ) = o;
        }
    }
}

extern "C" void kernel_launch(void* const* d_in, const int* in_sizes, int n_in,
                              void* d_out, int out_size, void* d_ws, size_t ws_size,
                              hipStream_t stream) {
    const float* inputs   = (const float*)d_in[0];
    const float* codebook = (const float*)d_in[1];
    float* out = (float*)d_out;
    unsigned short* cb_swz = (unsigned short*)d_ws;                                  // 2 MB
    float* norms = (float*)((char*)d_ws + (size_t)K_CODES * DIM * 2);                // 16 KB
    unsigned int* halfmin = (unsigned int*)((char*)d_ws + (size_t)K_CODES * DIM * 2
                                            + K_CODES * 4);                          // 512 KB
    float* loss_slot = out + (out_size - 1);

    hipLaunchKernelGGL(k_prep,   dim3(K_CODES / 32),   dim3(256), 0, stream,
                       codebook, cb_swz, norms, loss_slot);
    hipLaunchKernelGGL(k_argmin, dim3(NTOK / 256 * 2), dim3(256), 0, stream,
                       inputs, cb_swz, norms, halfmin, loss_slot);
    hipLaunchKernelGGL(k_gather, dim3(NTOK / 128),     dim3(256), 0, stream,
                       codebook, halfmin, out, loss_slot);
}

// Round 6
// 239.879 us; speedup vs baseline: 3.2373x; 3.0161x over previous
//
#include <hip/hip_runtime.h>

#define K_CODES 4096
#define DIM 256
#define SEQ 2048
#define NTOK 65536

typedef __bf16 bf16x8 __attribute__((ext_vector_type(8)));
typedef float floatx4 __attribute__((ext_vector_type(4)));
typedef unsigned short u16x8 __attribute__((ext_vector_type(8)));

__device__ __forceinline__ unsigned short f2bf(float f) {
    union { float f; unsigned int u; } v; v.f = f;
    unsigned int u = v.u;
    unsigned int r = u + 0x7fffu + ((u >> 16) & 1u);   // RNE
    return (unsigned short)(r >> 16);
}

// async global->LDS, 16B per lane. LDS dest = wave-uniform base + lane*16.
__device__ __forceinline__ void async_cp16(const void* g, const void* lds_base) {
    typedef __attribute__((address_space(1))) const unsigned int guint;
    typedef __attribute__((address_space(3))) unsigned int luint;
    __builtin_amdgcn_global_load_lds(
        (guint*)(unsigned long long)g,
        (luint*)(unsigned int)(unsigned long long)lds_base,
        16, 0, 0);
}

// ---------------- kernel 1: swizzled bf16 codebook + biased norms -----------
// cb_swz[((gc*16 + ns*8 + ks)*64 + quad*16 + col)*8 + j]
//   = bf16(codebook[gc*32 + ns*16 + col][quad*8 + ks*32 + j])
// norms[row] = ||e||^2 + 0.25 (bias keeps dist positive; exp ~ -2 -> key
// truncation quantum 2^-13..2^-14, well under the 2.2e-3 code-distance std)
__global__ __launch_bounds__(256) void k_prep(const float* __restrict__ cb,
        unsigned short* __restrict__ cb_swz, float* __restrict__ norms,
        float* __restrict__ loss_slot) {
    const int c = blockIdx.x;
    const int t = threadIdx.x;
    const int row_loc = t >> 3;       // 0..31 code within chunk
    const int ks = t & 7;             // k-slice
    const int row = c * 32 + row_loc;
    const float* src = cb + (size_t)row * DIM + ks * 32;
    float vals[32];
    float s = 0.0f;
    #pragma unroll
    for (int i = 0; i < 8; ++i) {
        floatx4 v = *(const floatx4*)(src + i * 4);
        #pragma unroll
        for (int j = 0; j < 4; ++j) { vals[i * 4 + j] = v[j]; s += v[j] * v[j]; }
    }
    const int ns = row_loc >> 4, col = row_loc & 15;
    #pragma unroll
    for (int quad = 0; quad < 4; ++quad) {
        u16x8 p;
        #pragma unroll
        for (int j = 0; j < 8; ++j) p[j] = f2bf(vals[quad * 8 + j]);
        *(u16x8*)(cb_swz + ((size_t)((c * 16 + ns * 8 + ks) * 64 + quad * 16 + col)) * 8) = p;
    }
    s += __shfl_xor(s, 1); s += __shfl_xor(s, 2); s += __shfl_xor(s, 4);
    if (ks == 0) norms[row] = s + 0.25f;
    if (c == 0 && t == 0) *loss_slot = 0.0f;
}

// ---------------- kernel 2: MFMA distance GEMM + packed argmin --------------
// ROUND-0 VERBATIM (verified 139us, af in AGPRs, no spill). 256 thr = 4 waves,
// 256 tokens/block (64/wave, m=4). Codes split in halves: grid 512 = 2
// blocks/CU co-resident. B staged once per block into a conflict-free LDS
// ring via global_load_lds -> 4-way cross-wave reuse.
__global__ __launch_bounds__(256, 2) void k_argmin(const float* __restrict__ x,
        const unsigned short* __restrict__ cb_swz, const float* __restrict__ norms,
        unsigned int* __restrict__ halfmin, float* __restrict__ loss_slot) {
    __shared__ __align__(16) unsigned short xs[64 * 264];    // 33792 B: X stage
    __shared__ __align__(16) unsigned short ring[2][8192];   // 32768 B: B ring
    __shared__ float wpart[4];
    const int t = threadIdx.x;
    const int lane = t & 63, w = t >> 6;
    const int col = lane & 15, quad = lane >> 4;
    const int bx = blockIdx.x;
    const int h = bx & 1;                  // code half
    const int tb = (bx >> 1) * 256;        // first token of block
    const int b = tb >> 11, s0 = tb & 2047;
    const float* xin = x + (size_t)b * DIM * SEQ;

    // prefetch B chunk 0 of this half into ring[0] (overlaps X staging)
    {
        const char* src = (const char*)cb_swz + (size_t)h * 64 * 16384;
        #pragma unroll
        for (int i = 0; i < 4; ++i)
            async_cp16(src + i * 4096 + w * 1024 + lane * 16,
                       (char*)ring[0] + i * 4096 + w * 1024);
    }

    // ---- X staging: 4 phases x 64 tokens; wave ph grabs its A fragments.
    // Also accumulate ||x||^2 over the whole block (for algebraic loss).
    bf16x8 af[4][8];
    float a2 = 0.0f;
    const int dg = t >> 4, sq = (t & 15) * 4;
    for (int ph = 0; ph < 4; ++ph) {
        const int sbase = s0 + ph * 64 + sq;
        for (int i = 0; i < 16; ++i) {
            int d = i * 16 + dg;
            floatx4 v = *(const floatx4*)(xin + (size_t)d * SEQ + sbase);
            a2 += v[0]*v[0] + v[1]*v[1] + v[2]*v[2] + v[3]*v[3];
            #pragma unroll
            for (int j = 0; j < 4; ++j) xs[(sq + j) * 264 + d] = f2bf(-2.0f * v[j]);
        }
        __syncthreads();
        if (w == ph) {
            #pragma unroll
            for (int m = 0; m < 4; ++m)
                #pragma unroll
                for (int ks = 0; ks < 8; ++ks)
                    af[m][ks] = *(const bf16x8*)&xs[(m * 16 + col) * 264
                                                    + quad * 8 + ks * 32];
        }
        __syncthreads();
    }
    // block-reduce a2; h==0 blocks contribute ||x||^2 part of the loss
    #pragma unroll
    for (int off = 1; off < 64; off <<= 1) a2 += __shfl_xor(a2, off);
    if (lane == 0) wpart[w] = a2;
    __syncthreads();
    if (t == 0 && h == 0)
        atomicAdd(loss_slot,
                  (wpart[0] + wpart[1] + wpart[2] + wpart[3]) * (1.25f / 16777216.0f));

    unsigned int minkey[4][4];
    #pragma unroll
    for (int m = 0; m < 4; ++m)
        #pragma unroll
        for (int r = 0; r < 4; ++r) minkey[m][r] = 0xFFFFFFFFu;

    #pragma unroll 1
    for (int c = 0; c < 64; ++c) {
        __syncthreads();                       // ring[c&1] ready, readers of c-1 done
        if (c < 63) {
            const char* src = (const char*)cb_swz + (size_t)(h * 64 + c + 1) * 16384;
            char* dst = (char*)ring[(c + 1) & 1];
            #pragma unroll
            for (int i = 0; i < 4; ++i)
                async_cp16(src + i * 4096 + w * 1024 + lane * 16,
                           dst + i * 4096 + w * 1024);
        }
        const unsigned short* buf = ring[c & 1];
        #pragma unroll
        for (int ns = 0; ns < 2; ++ns) {
            const float nv = norms[(h * 64 + c) * 32 + ns * 16 + col];
            bf16x8 bfrag[8];
            #pragma unroll
            for (int ks = 0; ks < 8; ++ks)     // lane-contiguous 1KB: conflict-free
                bfrag[ks] = *(const bf16x8*)&buf[((ns * 8 + ks) * 64 + lane) * 8];
            floatx4 acc[4];
            #pragma unroll
            for (int m = 0; m < 4; ++m) acc[m] = (floatx4){nv, nv, nv, nv};
            #pragma unroll
            for (int ks = 0; ks < 8; ++ks)
                #pragma unroll
                for (int m = 0; m < 4; ++m)
                    acc[m] = __builtin_amdgcn_mfma_f32_16x16x32_bf16(
                                 af[m][ks], bfrag[ks], acc[m], 0, 0, 0);
            const unsigned int code = (unsigned int)((h * 64 + c) * 32 + ns * 16 + col);
            #pragma unroll
            for (int m = 0; m < 4; ++m)
                #pragma unroll
                for (int r = 0; r < 4; ++r) {
                    unsigned int key = (__float_as_uint(acc[m][r]) & 0xFFFFF000u) | code;
                    minkey[m][r] = key < minkey[m][r] ? key : minkey[m][r];
                }
        }
    }

    // ---- min over 16 column-lanes, write packed (dist|code) per token
    #pragma unroll
    for (int m = 0; m < 4; ++m)
        #pragma unroll
        for (int r = 0; r < 4; ++r) {
            unsigned int k = minkey[m][r];
            #pragma unroll
            for (int off = 8; off >= 1; off >>= 1) {
                unsigned int o = __shfl_xor(k, off);
                k = o < k ? o : k;
            }
            if (col == 0)
                halfmin[h * NTOK + tb + w * 64 + m * 16 + quad * 4 + r] = k;
        }
}

// ---------------- kernel 3: merge + vectorized gather + loss ----------------
// 256 thr, 128 tokens/block, grid 512. Thread roles: q = t>>3 (token quad:
// tokens q*4..+3), dg = t&7 (d-group). Loads are floatx4 from cb with 128B
// contiguous segments per codebook row (8 dg-lanes x 16B); a 4x4 register
// transpose (static indices) feeds floatx4 stores with 128B contiguous
// segments per output d-row. 4x fewer load instructions than the scalar
// gather; no LDS round-trip.
__global__ __launch_bounds__(256) void k_gather(const float* __restrict__ cb,
        const unsigned int* __restrict__ halfmin, float* __restrict__ out,
        float* __restrict__ loss_slot) {
    __shared__ int sidx[128];
    __shared__ float wp2[2];
    const int t = threadIdx.x;
    const int tb = blockIdx.x * 128;
    const int b = tb >> 11, s0 = tb & 2047;
    if (t < 128) {
        unsigned int k0 = halfmin[tb + t], k1 = halfmin[NTOK + tb + t];
        unsigned int km = k0 < k1 ? k0 : k1;
        sidx[t] = (int)(km & 0xFFFu);
        float dv = __uint_as_float(km & 0xFFFFF000u) - 0.25f;
        #pragma unroll
        for (int off = 1; off < 64; off <<= 1) dv += __shfl_xor(dv, off);
        if ((t & 63) == 0) wp2[t >> 6] = dv;
    }
    __syncthreads();
    if (t == 0) atomicAdd(loss_slot, (wp2[0] + wp2[1]) * (1.25f / 16777216.0f));
    const int q = t >> 3, dg = t & 7;
    int rows[4];
    #pragma unroll
    for (int k = 0; k < 4; ++k) rows[k] = sidx[q * 4 + k];
    float* ob = out + (size_t)b * DIM * SEQ + s0 + q * 4;
    #pragma unroll
    for (int i = 0; i < 8; ++i) {
        const int d0 = i * 32 + dg * 4;
        floatx4 v0 = *(const floatx4*)(cb + (size_t)rows[0] * DIM + d0);
        floatx4 v1 = *(const floatx4*)(cb + (size_t)rows[1] * DIM + d0);
        floatx4 v2 = *(const floatx4*)(cb + (size_t)rows[2] * DIM + d0);
        floatx4 v3 = *(const floatx4*)(cb + (size_t)rows[3] * DIM + d0);
        #pragma unroll
        for (int j = 0; j < 4; ++j) {
            floatx4 o = {v0[j], v1[j], v2[j], v3[j]};
            *(floatx4*)(ob + (size_t)(d0 + j) * SEQ) = o;
        }
    }
}

extern "C" void kernel_launch(void* const* d_in, const int* in_sizes, int n_in,
                              void* d_out, int out_size, void* d_ws, size_t ws_size,
                              hipStream_t stream) {
    const float* inputs   = (const float*)d_in[0];
    const float* codebook = (const float*)d_in[1];
    float* out = (float*)d_out;
    unsigned short* cb_swz = (unsigned short*)d_ws;                                  // 2 MB
    float* norms = (float*)((char*)d_ws + (size_t)K_CODES * DIM * 2);                // 16 KB
    unsigned int* halfmin = (unsigned int*)((char*)d_ws + (size_t)K_CODES * DIM * 2
                                            + K_CODES * 4);                          // 512 KB
    float* loss_slot = out + (out_size - 1);

    hipLaunchKernelGGL(k_prep,   dim3(K_CODES / 32),   dim3(256), 0, stream,
                       codebook, cb_swz, norms, loss_slot);
    hipLaunchKernelGGL(k_argmin, dim3(NTOK / 256 * 2), dim3(256), 0, stream,
                       inputs, cb_swz, norms, halfmin, loss_slot);
    hipLaunchKernelGGL(k_gather, dim3(NTOK / 128),     dim3(256), 0, stream,
                       codebook, halfmin, out, loss_slot);
}